// Round 1
// baseline (2239.640 us; speedup 1.0000x reference)
//
#include <hip/hip_runtime.h>
#include <stdint.h>

// PyramidAttention on gfx950 — round 1: correctness-first MFMA pipeline.
// S-GEMM (scores) + online softmax stats (pass A, split over L in 2 halves),
// recompute S -> P -> Z-GEMM with atomics (pass B), then 9-tap gather + residual.

typedef __attribute__((ext_vector_type(8))) short bf16x8;
typedef __attribute__((ext_vector_type(4))) float f32x4;
typedef unsigned short ushort_t;

#define L_TOT 13326
#define L_PAD 13344   // 417 chunks * 32
#define NPIX  4096
#define NCHUNK 417

__device__ __forceinline__ float cubw(float d) {
  d = fabsf(d);
  if (d <= 1.f) return (1.25f * d - 2.25f) * d * d + 1.f;          // A=-0.75
  if (d < 2.f)  return ((-0.75f * d + 3.75f) * d - 6.f) * d + 3.f;
  return 0.f;
}

// l -> (scale size S, offset of scale in concatenated L)
__device__ __forceinline__ void decode_l(int l, int& S, int& off) {
  if (l < 4096)       { S = 64; off = 0; }
  else if (l < 7345)  { S = 57; off = 4096; }
  else if (l < 9946)  { S = 51; off = 7345; }
  else if (l < 11882) { S = 44; off = 9946; }
  else                { S = 38; off = 11882; }
}

__device__ __forceinline__ ushort_t f2bf(float f) {
  union { float f; uint32_t u; } v; v.f = f;
  uint32_t r = (v.u + 0x7fffu + ((v.u >> 16) & 1u)) >> 16;  // RNE
  return (ushort_t)r;
}

__device__ __forceinline__ float preluf(float x, float a) { return x >= 0.f ? x : a * x; }

// ---------------- K1: bicubic resize (align_corners=True, border clamp) ----------------
__global__ void k_resize(const float* __restrict__ inref, float* __restrict__ refbuf, int n) {
  int idx = blockIdx.x * 256 + threadIdx.x;
  if (idx >= n) return;                      // n = 2*64*L_TOT, idx -> (b*64+c, l)
  int l = idx % L_TOT; int bc = idx / L_TOT;
  int S, off; decode_l(l, S, off);
  int li = l - off; int ly = li / S, lx = li % S;
  float val;
  if (S == 64) {
    val = inref[(size_t)bc * 4096 + ly * 64 + lx];   // identity scale
  } else {
    float sc = (float)(63.0 / (double)(S - 1));
    float sy = (float)ly * sc, sx = (float)lx * sc;
    int iy = (int)floorf(sy), ix = (int)floorf(sx);
    float fy = sy - (float)iy, fx = sx - (float)ix;
    float wy[4] = { cubw(fy + 1.f), cubw(fy), cubw(1.f - fy), cubw(2.f - fy) };
    float wx[4] = { cubw(fx + 1.f), cubw(fx), cubw(1.f - fx), cubw(2.f - fx) };
    val = 0.f;
    for (int t = 0; t < 4; ++t) {
      int ty = iy - 1 + t; ty = ty < 0 ? 0 : (ty > 63 ? 63 : ty);
      float rv = 0.f;
      for (int u = 0; u < 4; ++u) {
        int tx = ix - 1 + u; tx = tx < 0 ? 0 : (tx > 63 ? 63 : tx);
        rv += wx[u] * inref[(size_t)bc * 4096 + ty * 64 + tx];
      }
      val += wy[t] * rv;
    }
  }
  refbuf[(size_t)bc * L_TOT + l] = val;
}

// ---------------- K2: conv1x1 (Wm->mref 32ch, Wa->aref 64ch) + prelu on ref pyramid ----------------
__global__ void k_convref(const float* __restrict__ refbuf,
                          const float* __restrict__ Wm, const float* __restrict__ bm,
                          const float* __restrict__ Wa, const float* __restrict__ ba,
                          const float* __restrict__ ap,
                          float* __restrict__ mref, float* __restrict__ aref, int n) {
  int idx = blockIdx.x * 256 + threadIdx.x;
  if (idx >= n) return;                      // n = 2*96*L_TOT
  int l = idx % L_TOT; int ch = (idx / L_TOT) % 96; int b = idx / (96 * L_TOT);
  float a = ap[0];
  const float* base = refbuf + (size_t)b * 64 * L_TOT + l;
  const float* Wrow; float acc;
  if (ch < 32) { Wrow = Wm + ch * 64; acc = bm[ch]; }
  else         { Wrow = Wa + (ch - 32) * 64; acc = ba[ch - 32]; }
  for (int c = 0; c < 64; ++c) acc += Wrow[c] * base[(size_t)c * L_TOT];
  acc = preluf(acc, a);
  if (ch < 32) mref[(size_t)(b * 32 + ch) * L_TOT + l] = acc;
  else         aref[(size_t)(b * 64 + ch - 32) * L_TOT + l] = acc;
}

// ---------------- K3: match_base = prelu(Wb@input+bb) ----------------
__global__ void k_mb(const float* __restrict__ input, const float* __restrict__ Wb,
                     const float* __restrict__ bb, const float* __restrict__ ap,
                     float* __restrict__ mbb, int n) {
  int idx = blockIdx.x * 256 + threadIdx.x;
  if (idx >= n) return;                      // n = 2*32*NPIX
  int p = idx % NPIX; int cm = (idx / NPIX) % 32; int b = idx / (32 * NPIX);
  float a = ap[0];
  float acc = bb[cm];
  for (int c = 0; c < 64; ++c) acc += Wb[cm * 64 + c] * input[(size_t)(b * 64 + c) * NPIX + p];
  mbb[(size_t)(b * 32 + cm) * NPIX + p] = preluf(acc, a);
}

// ---------------- K4a: per-position sum of squares of mref ----------------
__global__ void k_ssq(const float* __restrict__ mref, float* __restrict__ ssq, int n) {
  int idx = blockIdx.x * 256 + threadIdx.x;
  if (idx >= n) return;                      // n = 2*L_TOT
  int l = idx % L_TOT; int b = idx / L_TOT;
  float s = 0.f;
  for (int c = 0; c < 32; ++c) { float v = mref[(size_t)(b * 32 + c) * L_TOT + l]; s += v * v; }
  ssq[idx] = s;
}

// ---------------- K4b: 3x3 window sum (zero pad) -> 1/max(sqrt, 1e-4) ----------------
__global__ void k_invn(const float* __restrict__ ssq, float* __restrict__ invn, int n) {
  int idx = blockIdx.x * 256 + threadIdx.x;
  if (idx >= n) return;
  int l = idx % L_TOT; int b = idx / L_TOT;
  int S, off; decode_l(l, S, off);
  int li = l - off; int ly = li / S, lx = li % S;
  float acc = 0.f;
  for (int dy = -1; dy <= 1; ++dy) {
    int ny = ly + dy; if (ny < 0 || ny >= S) continue;
    for (int dx = -1; dx <= 1; ++dx) {
      int nx = lx + dx; if (nx < 0 || nx >= S) continue;
      acc += ssq[(size_t)b * L_TOT + off + ny * S + nx];
    }
  }
  float nrm = sqrtf(acc); nrm = fmaxf(nrm, 1e-4f);
  invn[idx] = 1.f / nrm;
}

// ---------------- K5: B im2col (normalized key patches) bf16 [b][l][288] ----------------
__global__ void k_bim(const float* __restrict__ mref, const float* __restrict__ invn,
                      ushort_t* __restrict__ Bm, int n) {
  int idx = blockIdx.x * 256 + threadIdx.x;
  if (idx >= n) return;                      // n = 2*L_TOT*288; k = c*9 + (dy+1)*3 + (dx+1)
  int k = idx % 288; int l = (idx / 288) % L_TOT; int b = idx / (288 * L_TOT);
  int c = k / 9; int r = k % 9; int dy = r / 3 - 1, dx = r % 3 - 1;
  int S, off; decode_l(l, S, off);
  int li = l - off; int ly = li / S, lx = li % S;
  int ny = ly + dy, nx = lx + dx;
  float v = 0.f;
  if (ny >= 0 && ny < S && nx >= 0 && nx < S)
    v = mref[(size_t)(b * 32 + c) * L_TOT + off + ny * S + nx] * invn[(size_t)b * L_TOT + l];
  Bm[(size_t)(b * L_TOT + l) * 288 + k] = f2bf(v);
}

// ---------------- K6: A im2col (query patches of match_base) bf16 [b][p][288] ----------------
__global__ void k_aim(const float* __restrict__ mbb, ushort_t* __restrict__ Am, int n) {
  int idx = blockIdx.x * 256 + threadIdx.x;
  if (idx >= n) return;                      // n = 2*NPIX*288
  int k = idx % 288; int p = (idx / 288) % NPIX; int b = idx / (288 * NPIX);
  int c = k / 9; int r = k % 9; int dy = r / 3 - 1, dx = r % 3 - 1;
  int y = p / 64, x = p % 64;
  int ny = y + dy, nx = x + dx;
  float v = 0.f;
  if (ny >= 0 && ny < 64 && nx >= 0 && nx < 64)
    v = mbb[(size_t)(b * 32 + c) * NPIX + ny * 64 + nx];
  Am[(size_t)(b * NPIX + p) * 288 + k] = f2bf(v);
}

// ---------------- K7: R im2col (value patches), col-major over l, zero-padded to L_PAD ----------------
__global__ void k_rim(const float* __restrict__ aref, ushort_t* __restrict__ Rm, int n) {
  int idx = blockIdx.x * 256 + threadIdx.x;
  if (idx >= n) return;                      // n = 2*576*L_PAD; col = c*9 + j*3 + i
  int l = idx % L_PAD; int col = (idx / L_PAD) % 576; int b = idx / (576 * L_PAD);
  float v = 0.f;
  if (l < L_TOT) {
    int c = col / 9; int r = col % 9; int dy = r / 3 - 1, dx = r % 3 - 1;
    int S, off; decode_l(l, S, off);
    int li = l - off; int ly = li / S, lx = li % S;
    int ny = ly + dy, nx = lx + dx;
    if (ny >= 0 && ny < S && nx >= 0 && nx < S)
      v = aref[(size_t)(b * 64 + c) * L_TOT + off + ny * S + nx];
  }
  Rm[(size_t)(b * 576 + col) * L_PAD + l] = f2bf(v);
}

// ---------------- K8: pass A — S tiles + online (max, sum exp) per pixel row ----------------
// grid 512: blockIdx -> {half(1b), tile(7b), b(1b)}; 256 thr = 4 waves; Mt=32 pixels, Kc=32 l.
__global__ __launch_bounds__(256) void k_passA(const ushort_t* __restrict__ Am,
                                               const ushort_t* __restrict__ Bm,
                                               float* __restrict__ rowm_p,
                                               float* __restrict__ rows_p) {
  __shared__ float Sb[32][33];
  __shared__ float mrun[32], srun[32];
  int tid = threadIdx.x;
  int half = blockIdx.x & 1; int tile = (blockIdx.x >> 1) & 127; int b = blockIdx.x >> 8;
  int p0 = tile * 32;
  int wave = tid >> 6, lane = tid & 63, quad = lane >> 4, ln = lane & 15;
  int rb = wave & 1, cb = wave >> 1;

  // A fragments (9 k-steps) held in registers for the whole kernel
  bf16x8 af[9];
  {
    const ushort_t* arow = Am + (size_t)(b * NPIX + p0 + rb * 16 + ln) * 288;
    for (int kk = 0; kk < 9; ++kk) af[kk] = *(const bf16x8*)(arow + kk * 32 + quad * 8);
  }
  if (tid < 32) { mrun[tid] = -1e30f; srun[tid] = 0.f; }

  bf16x8 bz; for (int z = 0; z < 8; ++z) bz[z] = 0;
  int c0 = half ? 209 : 0, c1 = half ? NCHUNK : 209;
  for (int ch = c0; ch < c1; ++ch) {
    int lbase = ch * 32;
    __syncthreads();   // protect Sb from previous stats read
    // S tile: B fragments straight from global (L2-resident)
    f32x4 s; s[0] = s[1] = s[2] = s[3] = 0.f;
    int lcol = lbase + cb * 16 + ln;
    bool lv = lcol < L_TOT;
    const ushort_t* brow = Bm + (size_t)(b * L_TOT + (lv ? lcol : 0)) * 288;
    for (int kk = 0; kk < 9; ++kk) {
      bf16x8 bfr = lv ? *(const bf16x8*)(brow + kk * 32 + quad * 8) : bz;
      s = __builtin_amdgcn_mfma_f32_16x16x32_bf16(af[kk], bfr, s, 0, 0, 0);
    }
    for (int r = 0; r < 4; ++r) Sb[rb * 16 + quad * 4 + r][cb * 16 + ln] = s[r];
    __syncthreads();
    // stats: 8 threads per row, 4 cols each (all 8 in one wave)
    int row = tid >> 3, sub = tid & 7;
    float sv[4]; float cmax = -1e30f;
    for (int j = 0; j < 4; ++j) {
      int l = lbase + sub * 4 + j;
      sv[j] = (l < L_TOT) ? Sb[row][sub * 4 + j] : -1e30f;
      cmax = fmaxf(cmax, sv[j]);
    }
    cmax = fmaxf(cmax, __shfl_xor(cmax, 1));
    cmax = fmaxf(cmax, __shfl_xor(cmax, 2));
    cmax = fmaxf(cmax, __shfl_xor(cmax, 4));
    float mo = mrun[row];
    float mn = fmaxf(mo, cmax);
    float es = 0.f;
    for (int j = 0; j < 4; ++j) {
      int l = lbase + sub * 4 + j;
      if (l < L_TOT) es += expf(10.f * (sv[j] - mn));
    }
    es += __shfl_xor(es, 1); es += __shfl_xor(es, 2); es += __shfl_xor(es, 4);
    if (sub == 0) { srun[row] = srun[row] * expf(10.f * (mo - mn)) + es; mrun[row] = mn; }
  }
  __syncthreads();
  if (tid < 32) {
    int g = (half * 2 + b) * NPIX + p0 + tid;
    rowm_p[g] = mrun[tid]; rows_p[g] = srun[tid];
  }
}

// ---------------- K8b: merge the two l-halves (log-sum-exp) ----------------
__global__ void k_merge(const float* __restrict__ rowm_p, const float* __restrict__ rows_p,
                        float* __restrict__ rowm_g, float* __restrict__ rowi_g, int n) {
  int idx = blockIdx.x * 256 + threadIdx.x;
  if (idx >= n) return;                      // n = 2*NPIX; idx = b*NPIX+p
  int b = idx / NPIX; int p = idx % NPIX;
  float m0 = rowm_p[b * NPIX + p],      s0 = rows_p[b * NPIX + p];
  float m1 = rowm_p[(2 + b) * NPIX + p], s1 = rows_p[(2 + b) * NPIX + p];
  float m = fmaxf(m0, m1);
  float sum = s0 * expf(10.f * (m0 - m)) + s1 * expf(10.f * (m1 - m));
  rowm_g[idx] = m; rowi_g[idx] = 1.f / sum;
}

__global__ void k_zero(float* __restrict__ Zg, int n) {
  int idx = blockIdx.x * 256 + threadIdx.x;
  if (idx < n) Zg[idx] = 0.f;
}

// ---------------- K9: pass B — recompute S, P=softmax, Z += P@R ----------------
__global__ __launch_bounds__(256) void k_passB(const ushort_t* __restrict__ Am,
                                               const ushort_t* __restrict__ Bm,
                                               const ushort_t* __restrict__ Rm,
                                               const float* __restrict__ rowm_g,
                                               const float* __restrict__ rowi_g,
                                               float* __restrict__ Zg) {
  __shared__ ushort_t Rb[576][40];   // value chunk, +8 pad (16B-aligned rows, ~2-way banks)
  __shared__ ushort_t Pb[32][40];    // probability tile (A-operand layout for Z-GEMM)
  __shared__ float mF[32], iF[32];
  int tid = threadIdx.x;
  int half = blockIdx.x & 1; int tile = (blockIdx.x >> 1) & 127; int b = blockIdx.x >> 8;
  int p0 = tile * 32;
  int wave = tid >> 6, lane = tid & 63, quad = lane >> 4, ln = lane & 15;
  int rb = wave & 1, cb = wave >> 1;
  int zc0 = (wave >> 1) * 18;        // 18 col-blocks of 16 per wave (576 = 2*18*16)

  bf16x8 af[9];
  {
    const ushort_t* arow = Am + (size_t)(b * NPIX + p0 + rb * 16 + ln) * 288;
    for (int kk = 0; kk < 9; ++kk) af[kk] = *(const bf16x8*)(arow + kk * 32 + quad * 8);
  }
  if (tid < 32) {
    mF[tid] = rowm_g[b * NPIX + p0 + tid];
    iF[tid] = rowi_g[b * NPIX + p0 + tid];
  }
  f32x4 acc[18];
  for (int t = 0; t < 18; ++t) { acc[t][0] = acc[t][1] = acc[t][2] = acc[t][3] = 0.f; }

  bf16x8 bz; for (int z = 0; z < 8; ++z) bz[z] = 0;
  int c0 = half ? 209 : 0, c1 = half ? NCHUNK : 209;
  for (int ch = c0; ch < c1; ++ch) {
    int lbase = ch * 32;
    __syncthreads();   // prev iteration finished reading Rb/Pb
    // stage R chunk [576 cols][32 l] (Rm zero-padded to L_PAD: no tail guard)
    for (int i = tid; i < 2304; i += 256) {
      int col = i >> 2, seg = i & 3;
      uint4 v = *(const uint4*)(Rm + (size_t)(b * 576 + col) * L_PAD + lbase + seg * 8);
      *(uint4*)&Rb[col][seg * 8] = v;
    }
    // S tile (identical sequence to pass A -> exponents <= 0)
    f32x4 s; s[0] = s[1] = s[2] = s[3] = 0.f;
    int lcol = lbase + cb * 16 + ln;
    bool lv = lcol < L_TOT;
    const ushort_t* brow = Bm + (size_t)(b * L_TOT + (lv ? lcol : 0)) * 288;
    for (int kk = 0; kk < 9; ++kk) {
      bf16x8 bfr = lv ? *(const bf16x8*)(brow + kk * 32 + quad * 8) : bz;
      s = __builtin_amdgcn_mfma_f32_16x16x32_bf16(af[kk], bfr, s, 0, 0, 0);
    }
    for (int r = 0; r < 4; ++r) {
      int row = rb * 16 + quad * 4 + r;
      float pv = 0.f;
      if (lv) pv = expf(10.f * (s[r] - mF[row])) * iF[row];
      Pb[row][cb * 16 + ln] = f2bf(pv);
    }
    __syncthreads();   // Rb + Pb ready
    bf16x8 pf = *(const bf16x8*)&Pb[rb * 16 + ln][quad * 8];
    for (int t = 0; t < 18; ++t) {
      bf16x8 bfr = *(const bf16x8*)&Rb[(zc0 + t) * 16 + ln][quad * 8];
      acc[t] = __builtin_amdgcn_mfma_f32_16x16x32_bf16(pf, bfr, acc[t], 0, 0, 0);
    }
  }
  // accumulate into global Z (two l-halves) — Zg pre-zeroed
  for (int t = 0; t < 18; ++t) {
    int colb = (zc0 + t) * 16 + ln;
    for (int r = 0; r < 4; ++r) {
      int row = p0 + rb * 16 + quad * 4 + r;
      atomicAdd(&Zg[(size_t)(b * NPIX + row) * 576 + colb], acc[t][r]);
    }
  }
}

// ---------------- K10: 9-tap gather of Z (conv-transpose), /4, + residual ----------------
__global__ void k_final(const float* __restrict__ Zg, const float* __restrict__ input,
                        float* __restrict__ out, int n) {
  int idx = blockIdx.x * 256 + threadIdx.x;
  if (idx >= n) return;                      // n = 2*64*NPIX, idx = ((b*64+c)*64+y)*64+x
  int x = idx & 63; int y = (idx >> 6) & 63; int c = (idx >> 12) & 63; int b = idx >> 18;
  float acc = 0.f;
  for (int j = 0; j < 3; ++j) {
    int qy = y + 1 - j; if (qy < 0 || qy >= 64) continue;
    for (int i = 0; i < 3; ++i) {
      int qx = x + 1 - i; if (qx < 0 || qx >= 64) continue;
      acc += Zg[(size_t)(b * NPIX + qy * 64 + qx) * 576 + c * 9 + j * 3 + i];
    }
  }
  out[idx] = 0.25f * acc + input[idx];
}

extern "C" void kernel_launch(void* const* d_in, const int* in_sizes, int n_in,
                              void* d_out, int out_size, void* d_ws, size_t ws_size,
                              hipStream_t stream) {
  (void)in_sizes; (void)n_in; (void)out_size;
  const float* input = (const float*)d_in[0];
  const float* inref = (const float*)d_in[1];
  const float* Wb = (const float*)d_in[2];
  const float* bb = (const float*)d_in[3];
  const float* Wm = (const float*)d_in[4];
  const float* bm = (const float*)d_in[5];
  const float* Wa = (const float*)d_in[6];
  const float* ba = (const float*)d_in[7];
  const float* ap = (const float*)d_in[8];
  float* out = (float*)d_out;

  char* ws = (char*)d_ws;
  size_t off = 0;
  auto alloc = [&](size_t bytes) -> char* {
    char* p = ws + off; off = (off + bytes + 255) & ~(size_t)255; return p;
  };
  float*    refbuf = (float*)alloc((size_t)2 * 64 * L_TOT * 4);
  float*    mref   = (float*)alloc((size_t)2 * 32 * L_TOT * 4);
  float*    aref   = (float*)alloc((size_t)2 * 64 * L_TOT * 4);
  float*    mbb    = (float*)alloc((size_t)2 * 32 * NPIX * 4);
  float*    ssq    = (float*)alloc((size_t)2 * L_TOT * 4);
  float*    invn   = (float*)alloc((size_t)2 * L_TOT * 4);
  ushort_t* Am     = (ushort_t*)alloc((size_t)2 * NPIX * 288 * 2);
  ushort_t* Bm     = (ushort_t*)alloc((size_t)2 * L_TOT * 288 * 2);
  ushort_t* Rm     = (ushort_t*)alloc((size_t)2 * 576 * L_PAD * 2);
  float*    rowm_p = (float*)alloc((size_t)4 * NPIX * 4);
  float*    rows_p = (float*)alloc((size_t)4 * NPIX * 4);
  float*    rowm_g = (float*)alloc((size_t)2 * NPIX * 4);
  float*    rowi_g = (float*)alloc((size_t)2 * NPIX * 4);
  float*    Zg     = (float*)alloc((size_t)2 * NPIX * 576 * 4);
  (void)ws_size;  // total ~88 MB

  int n1 = 2 * 64 * L_TOT;
  k_resize<<<(n1 + 255) / 256, 256, 0, stream>>>(inref, refbuf, n1);
  int n2 = 2 * 96 * L_TOT;
  k_convref<<<(n2 + 255) / 256, 256, 0, stream>>>(refbuf, Wm, bm, Wa, ba, ap, mref, aref, n2);
  int n3 = 2 * 32 * NPIX;
  k_mb<<<(n3 + 255) / 256, 256, 0, stream>>>(input, Wb, bb, ap, mbb, n3);
  int n4 = 2 * L_TOT;
  k_ssq<<<(n4 + 255) / 256, 256, 0, stream>>>(mref, ssq, n4);
  k_invn<<<(n4 + 255) / 256, 256, 0, stream>>>(ssq, invn, n4);
  int n5 = 2 * L_TOT * 288;
  k_bim<<<(n5 + 255) / 256, 256, 0, stream>>>(mref, invn, Bm, n5);
  int n6 = 2 * NPIX * 288;
  k_aim<<<(n6 + 255) / 256, 256, 0, stream>>>(mbb, Am, n6);
  int n7 = 2 * 576 * L_PAD;
  k_rim<<<(n7 + 255) / 256, 256, 0, stream>>>(aref, Rm, n7);

  k_passA<<<512, 256, 0, stream>>>(Am, Bm, rowm_p, rows_p);
  k_merge<<<(2 * NPIX + 255) / 256, 256, 0, stream>>>(rowm_p, rows_p, rowm_g, rowi_g, 2 * NPIX);
  int nz = 2 * NPIX * 576;
  k_zero<<<(nz + 255) / 256, 256, 0, stream>>>(Zg, nz);
  k_passB<<<512, 256, 0, stream>>>(Am, Bm, Rm, rowm_g, rowi_g, Zg);
  int no = 2 * 64 * NPIX;
  k_final<<<(no + 255) / 256, 256, 0, stream>>>(Zg, input, out, no);
}

// Round 2
// 871.381 us; speedup vs baseline: 2.5702x; 2.5702x over previous
//
#include <hip/hip_runtime.h>
#include <stdint.h>

// PyramidAttention on gfx950 — round 2: single-pass flash attention kernel.
// Online softmax in registers/shuffles, Kc=64, direct-global R fragments,
// tiny LDS (P tile + stats exchange), per-split O + (m,l), fused merge in final.

typedef __attribute__((ext_vector_type(8))) short bf16x8;
typedef __attribute__((ext_vector_type(4))) float f32x4;
typedef unsigned short ushort_t;

#define L_TOT 13326
#define L_PAD2 13376   // 209 chunks * 64
#define NPIX  4096
#define NCH64 209
#define NSPLIT 2

__device__ __forceinline__ float cubw(float d) {
  d = fabsf(d);
  if (d <= 1.f) return (1.25f * d - 2.25f) * d * d + 1.f;          // A=-0.75
  if (d < 2.f)  return ((-0.75f * d + 3.75f) * d - 6.f) * d + 3.f;
  return 0.f;
}

__device__ __forceinline__ void decode_l(int l, int& S, int& off) {
  if (l < 4096)       { S = 64; off = 0; }
  else if (l < 7345)  { S = 57; off = 4096; }
  else if (l < 9946)  { S = 51; off = 7345; }
  else if (l < 11882) { S = 44; off = 9946; }
  else                { S = 38; off = 11882; }
}

__device__ __forceinline__ ushort_t f2bf(float f) {
  union { float f; uint32_t u; } v; v.f = f;
  uint32_t r = (v.u + 0x7fffu + ((v.u >> 16) & 1u)) >> 16;  // RNE
  return (ushort_t)r;
}

__device__ __forceinline__ float preluf(float x, float a) { return x >= 0.f ? x : a * x; }

// ---------------- K1: bicubic resize (align_corners=True, border clamp) ----------------
__global__ void k_resize(const float* __restrict__ inref, float* __restrict__ refbuf, int n) {
  int idx = blockIdx.x * 256 + threadIdx.x;
  if (idx >= n) return;                      // n = 2*64*L_TOT, idx -> (b*64+c, l)
  int l = idx % L_TOT; int bc = idx / L_TOT;
  int S, off; decode_l(l, S, off);
  int li = l - off; int ly = li / S, lx = li % S;
  float val;
  if (S == 64) {
    val = inref[(size_t)bc * 4096 + ly * 64 + lx];
  } else {
    float sc = (float)(63.0 / (double)(S - 1));
    float sy = (float)ly * sc, sx = (float)lx * sc;
    int iy = (int)floorf(sy), ix = (int)floorf(sx);
    float fy = sy - (float)iy, fx = sx - (float)ix;
    float wy[4] = { cubw(fy + 1.f), cubw(fy), cubw(1.f - fy), cubw(2.f - fy) };
    float wx[4] = { cubw(fx + 1.f), cubw(fx), cubw(1.f - fx), cubw(2.f - fx) };
    val = 0.f;
    for (int t = 0; t < 4; ++t) {
      int ty = iy - 1 + t; ty = ty < 0 ? 0 : (ty > 63 ? 63 : ty);
      float rv = 0.f;
      for (int u = 0; u < 4; ++u) {
        int tx = ix - 1 + u; tx = tx < 0 ? 0 : (tx > 63 ? 63 : tx);
        rv += wx[u] * inref[(size_t)bc * 4096 + ty * 64 + tx];
      }
      val += wy[t] * rv;
    }
  }
  refbuf[(size_t)bc * L_TOT + l] = val;
}

// ---------------- K2: conv1x1 (Wm->mref 32ch, Wa->aref 64ch) + prelu ----------------
__global__ void k_convref(const float* __restrict__ refbuf,
                          const float* __restrict__ Wm, const float* __restrict__ bm,
                          const float* __restrict__ Wa, const float* __restrict__ ba,
                          const float* __restrict__ ap,
                          float* __restrict__ mref, float* __restrict__ aref, int n) {
  int idx = blockIdx.x * 256 + threadIdx.x;
  if (idx >= n) return;                      // n = 2*96*L_TOT
  int l = idx % L_TOT; int ch = (idx / L_TOT) % 96; int b = idx / (96 * L_TOT);
  float a = ap[0];
  const float* base = refbuf + (size_t)b * 64 * L_TOT + l;
  const float* Wrow; float acc;
  if (ch < 32) { Wrow = Wm + ch * 64; acc = bm[ch]; }
  else         { Wrow = Wa + (ch - 32) * 64; acc = ba[ch - 32]; }
  for (int c = 0; c < 64; ++c) acc += Wrow[c] * base[(size_t)c * L_TOT];
  acc = preluf(acc, a);
  if (ch < 32) mref[(size_t)(b * 32 + ch) * L_TOT + l] = acc;
  else         aref[(size_t)(b * 64 + ch - 32) * L_TOT + l] = acc;
}

// ---------------- K3: match_base = prelu(Wb@input+bb) ----------------
__global__ void k_mb(const float* __restrict__ input, const float* __restrict__ Wb,
                     const float* __restrict__ bb, const float* __restrict__ ap,
                     float* __restrict__ mbb, int n) {
  int idx = blockIdx.x * 256 + threadIdx.x;
  if (idx >= n) return;                      // n = 2*32*NPIX
  int p = idx % NPIX; int cm = (idx / NPIX) % 32; int b = idx / (32 * NPIX);
  float a = ap[0];
  float acc = bb[cm];
  for (int c = 0; c < 64; ++c) acc += Wb[cm * 64 + c] * input[(size_t)(b * 64 + c) * NPIX + p];
  mbb[(size_t)(b * 32 + cm) * NPIX + p] = preluf(acc, a);
}

// ---------------- K4a: per-position sum of squares of mref ----------------
__global__ void k_ssq(const float* __restrict__ mref, float* __restrict__ ssq, int n) {
  int idx = blockIdx.x * 256 + threadIdx.x;
  if (idx >= n) return;                      // n = 2*L_TOT
  int l = idx % L_TOT; int b = idx / L_TOT;
  float s = 0.f;
  for (int c = 0; c < 32; ++c) { float v = mref[(size_t)(b * 32 + c) * L_TOT + l]; s += v * v; }
  ssq[idx] = s;
}

// ---------------- K4b: 3x3 window sum -> 1/max(sqrt, 1e-4) ----------------
__global__ void k_invn(const float* __restrict__ ssq, float* __restrict__ invn, int n) {
  int idx = blockIdx.x * 256 + threadIdx.x;
  if (idx >= n) return;
  int l = idx % L_TOT; int b = idx / L_TOT;
  int S, off; decode_l(l, S, off);
  int li = l - off; int ly = li / S, lx = li % S;
  float acc = 0.f;
  for (int dy = -1; dy <= 1; ++dy) {
    int ny = ly + dy; if (ny < 0 || ny >= S) continue;
    for (int dx = -1; dx <= 1; ++dx) {
      int nx = lx + dx; if (nx < 0 || nx >= S) continue;
      acc += ssq[(size_t)b * L_TOT + off + ny * S + nx];
    }
  }
  float nrm = sqrtf(acc); nrm = fmaxf(nrm, 1e-4f);
  invn[idx] = 1.f / nrm;
}

// ---------------- K5: B im2col (normalized key patches) bf16 [b][l][288] ----------------
__global__ void k_bim(const float* __restrict__ mref, const float* __restrict__ invn,
                      ushort_t* __restrict__ Bm, int n) {
  int idx = blockIdx.x * 256 + threadIdx.x;
  if (idx >= n) return;                      // n = 2*L_TOT*288
  int k = idx % 288; int l = (idx / 288) % L_TOT; int b = idx / (288 * L_TOT);
  int c = k / 9; int r = k % 9; int dy = r / 3 - 1, dx = r % 3 - 1;
  int S, off; decode_l(l, S, off);
  int li = l - off; int ly = li / S, lx = li % S;
  int ny = ly + dy, nx = lx + dx;
  float v = 0.f;
  if (ny >= 0 && ny < S && nx >= 0 && nx < S)
    v = mref[(size_t)(b * 32 + c) * L_TOT + off + ny * S + nx] * invn[(size_t)b * L_TOT + l];
  Bm[(size_t)(b * L_TOT + l) * 288 + k] = f2bf(v);
}

// ---------------- K6: A im2col (query patches) bf16 [b][p][288] ----------------
__global__ void k_aim(const float* __restrict__ mbb, ushort_t* __restrict__ Am, int n) {
  int idx = blockIdx.x * 256 + threadIdx.x;
  if (idx >= n) return;                      // n = 2*NPIX*288
  int k = idx % 288; int p = (idx / 288) % NPIX; int b = idx / (288 * NPIX);
  int c = k / 9; int r = k % 9; int dy = r / 3 - 1, dx = r % 3 - 1;
  int y = p / 64, x = p % 64;
  int ny = y + dy, nx = x + dx;
  float v = 0.f;
  if (ny >= 0 && ny < 64 && nx >= 0 && nx < 64)
    v = mbb[(size_t)(b * 32 + c) * NPIX + ny * 64 + nx];
  Am[(size_t)(b * NPIX + p) * 288 + k] = f2bf(v);
}

// ---------------- K7: R im2col (value patches), col-major over l, zero-padded ----------------
__global__ void k_rim(const float* __restrict__ aref, ushort_t* __restrict__ Rm, int n) {
  int idx = blockIdx.x * 256 + threadIdx.x;
  if (idx >= n) return;                      // n = 2*576*L_PAD2
  int l = idx % L_PAD2; int col = (idx / L_PAD2) % 576; int b = idx / (576 * L_PAD2);
  float v = 0.f;
  if (l < L_TOT) {
    int c = col / 9; int r = col % 9; int dy = r / 3 - 1, dx = r % 3 - 1;
    int S, off; decode_l(l, S, off);
    int li = l - off; int ly = li / S, lx = li % S;
    int ny = ly + dy, nx = lx + dx;
    if (ny >= 0 && ny < S && nx >= 0 && nx < S)
      v = aref[(size_t)(b * 64 + c) * L_TOT + off + ny * S + nx];
  }
  Rm[(size_t)(b * 576 + col) * L_PAD2 + l] = f2bf(v);
}

// ---------------- K8: single-pass flash attention ----------------
// grid 512: blockIdx -> tile(7b) | split(1b) | b(1b). 256 thr = 4 waves.
// M=32 pixels, Kc=64 l per chunk. S waves: (rb=wave&1 rows, cbh=wave>>1 l-half).
// Z waves: each wave owns cols [wave*144, wave*144+144), all 32 rows.
__global__ __launch_bounds__(256, 2) void k_attn(const ushort_t* __restrict__ Am,
                                                 const ushort_t* __restrict__ Bm,
                                                 const ushort_t* __restrict__ Rm,
                                                 float* __restrict__ Og,
                                                 float* __restrict__ Om,
                                                 float* __restrict__ Ol) {
  __shared__ ushort_t Pb[32][72];      // P tile, row-major over l (+8 pad)
  __shared__ float Mx[2][2][32];       // [parity][cbh][row] chunk max
  __shared__ float Sx[2][32];          // [cbh][row] chunk expsum
  int tid = threadIdx.x;
  int tile = blockIdx.x & 127; int split = (blockIdx.x >> 7) & 1; int b = blockIdx.x >> 8;
  int p0 = tile * 32;
  int wave = tid >> 6, lane = tid & 63, quad = lane >> 4, ln = lane & 15;
  int rb = wave & 1, cbh = wave >> 1;

  // A fragments resident (9 k-steps of 16x16x32 over K=288)
  bf16x8 af[9];
  {
    const ushort_t* arow = Am + (size_t)(b * NPIX + p0 + rb * 16 + ln) * 288;
    #pragma unroll
    for (int kk = 0; kk < 9; ++kk) af[kk] = *(const bf16x8*)(arow + kk * 32 + quad * 8);
  }

  f32x4 acc[2][9];
  #pragma unroll
  for (int h = 0; h < 2; ++h)
    #pragma unroll
    for (int t = 0; t < 9; ++t) { acc[h][t][0] = acc[h][t][1] = acc[h][t][2] = acc[h][t][3] = 0.f; }
  float mrun[2][4], lrun[4];
  #pragma unroll
  for (int h = 0; h < 2; ++h)
    #pragma unroll
    for (int r = 0; r < 4; ++r) mrun[h][r] = -1e30f;
  #pragma unroll
  for (int r = 0; r < 4; ++r) lrun[r] = 0.f;

  const size_t rstride = (size_t)16 * L_PAD2;
  const ushort_t* rbase0 = Rm + (size_t)(b * 576 + wave * 144 + ln) * L_PAD2 + quad * 8;

  int c0 = split ? 105 : 0, c1 = split ? NCH64 : 105;
  for (int ch = c0; ch < c1; ++ch) {
    int lbase = ch * 64;
    int par = ch & 1;
    // ---- S tile: rows rb*16+, cols [cbh*32, cbh*32+32) of this chunk ----
    int col0 = lbase + cbh * 32 + ln;
    int col1 = col0 + 16;
    bool v0 = col0 < L_TOT, v1 = col1 < L_TOT;
    const ushort_t* b0 = Bm + (size_t)(b * L_TOT + (v0 ? col0 : 0)) * 288 + quad * 8;
    const ushort_t* b1 = Bm + (size_t)(b * L_TOT + (v1 ? col1 : 0)) * 288 + quad * 8;
    f32x4 s0, s1;
    s0[0] = s0[1] = s0[2] = s0[3] = 0.f;
    s1[0] = s1[1] = s1[2] = s1[3] = 0.f;
    #pragma unroll
    for (int kk = 0; kk < 9; ++kk) {
      bf16x8 f0 = *(const bf16x8*)(b0 + kk * 32);
      bf16x8 f1 = *(const bf16x8*)(b1 + kk * 32);
      s0 = __builtin_amdgcn_mfma_f32_16x16x32_bf16(af[kk], f0, s0, 0, 0, 0);
      s1 = __builtin_amdgcn_mfma_f32_16x16x32_bf16(af[kk], f1, s1, 0, 0, 0);
    }
    // prefetch R frags for kb=0 (independent of stats)
    bf16x8 rpre[9];
    {
      const ushort_t* rb0 = rbase0 + lbase;
      #pragma unroll
      for (int t = 0; t < 9; ++t) rpre[t] = *(const bf16x8*)(rb0 + (size_t)t * rstride);
    }
    // ---- in-wave chunk max over this wave's 32 cols ----
    float cm[4];
    #pragma unroll
    for (int r = 0; r < 4; ++r)
      cm[r] = fmaxf(v0 ? s0[r] : -1e30f, v1 ? s1[r] : -1e30f);
    #pragma unroll
    for (int m = 1; m <= 8; m <<= 1)
      #pragma unroll
      for (int r = 0; r < 4; ++r) cm[r] = fmaxf(cm[r], __shfl_xor(cm[r], m));
    if (ln == 0) {
      #pragma unroll
      for (int r = 0; r < 4; ++r) Mx[par][cbh][rb * 16 + quad * 4 + r] = cm[r];
    }
    __syncthreads();   // B1: Mx ready
    // ---- running max update + alpha (all 32 rows, every wave redundantly) ----
    float alpha[2][4];
    #pragma unroll
    for (int h = 0; h < 2; ++h)
      #pragma unroll
      for (int r = 0; r < 4; ++r) {
        int row = h * 16 + quad * 4 + r;
        float mc = fmaxf(Mx[par][0][row], Mx[par][1][row]);
        float mn = fmaxf(mrun[h][r], mc);
        alpha[h][r] = __expf(10.f * (mrun[h][r] - mn));
        mrun[h][r] = mn;
      }
    // ---- P = exp(10(s-m)), store bf16 to Pb, partial row sums ----
    float ps[4];
    #pragma unroll
    for (int r = 0; r < 4; ++r) {
      int row = rb * 16 + quad * 4 + r;
      float p0v = v0 ? __expf(10.f * (s0[r] - mrun[rb][r])) : 0.f;
      float p1v = v1 ? __expf(10.f * (s1[r] - mrun[rb][r])) : 0.f;
      Pb[row][cbh * 32 + ln] = f2bf(p0v);
      Pb[row][cbh * 32 + 16 + ln] = f2bf(p1v);
      ps[r] = p0v + p1v;
    }
    #pragma unroll
    for (int m = 1; m <= 8; m <<= 1)
      #pragma unroll
      for (int r = 0; r < 4; ++r) ps[r] += __shfl_xor(ps[r], m);
    if (ln == 0) {
      #pragma unroll
      for (int r = 0; r < 4; ++r) Sx[cbh][rb * 16 + quad * 4 + r] = ps[r];
    }
    __syncthreads();   // B2: Pb + Sx ready
    // ---- l update (owner waves cbh==0 hold l for their rb rows) ----
    if (cbh == 0) {
      #pragma unroll
      for (int r = 0; r < 4; ++r) {
        int row = rb * 16 + quad * 4 + r;
        lrun[r] = lrun[r] * alpha[rb][r] + Sx[0][row] + Sx[1][row];
      }
    }
    // ---- rescale Z acc ----
    #pragma unroll
    for (int h = 0; h < 2; ++h)
      #pragma unroll
      for (int t = 0; t < 9; ++t)
        #pragma unroll
        for (int r = 0; r < 4; ++r) acc[h][t][r] *= alpha[h][r];
    // ---- Z-GEMM: P(32xKc) @ R(Kc x 144-per-wave) ----
    {
      bf16x8 pf0 = *(const bf16x8*)&Pb[ln][quad * 8];
      bf16x8 pf1 = *(const bf16x8*)&Pb[16 + ln][quad * 8];
      #pragma unroll
      for (int t = 0; t < 9; ++t) {
        acc[0][t] = __builtin_amdgcn_mfma_f32_16x16x32_bf16(pf0, rpre[t], acc[0][t], 0, 0, 0);
        acc[1][t] = __builtin_amdgcn_mfma_f32_16x16x32_bf16(pf1, rpre[t], acc[1][t], 0, 0, 0);
      }
      bf16x8 pf2 = *(const bf16x8*)&Pb[ln][32 + quad * 8];
      bf16x8 pf3 = *(const bf16x8*)&Pb[16 + ln][32 + quad * 8];
      const ushort_t* rb1 = rbase0 + lbase + 32;
      #pragma unroll
      for (int t = 0; t < 9; ++t) {
        bf16x8 rf = *(const bf16x8*)(rb1 + (size_t)t * rstride);
        acc[0][t] = __builtin_amdgcn_mfma_f32_16x16x32_bf16(pf2, rf, acc[0][t], 0, 0, 0);
        acc[1][t] = __builtin_amdgcn_mfma_f32_16x16x32_bf16(pf3, rf, acc[1][t], 0, 0, 0);
      }
    }
  }

  // ---- epilogue: write unnormalized O and stats ----
  int sb = split * 2 + b;
  #pragma unroll
  for (int h = 0; h < 2; ++h)
    #pragma unroll
    for (int t = 0; t < 9; ++t) {
      int colg = wave * 144 + t * 16 + ln;
      #pragma unroll
      for (int r = 0; r < 4; ++r) {
        int row = p0 + h * 16 + quad * 4 + r;
        Og[((size_t)sb * NPIX + row) * 576 + colg] = acc[h][t][r];
      }
    }
  if (cbh == 0 && ln == 0) {
    #pragma unroll
    for (int r = 0; r < 4; ++r) {
      int row = p0 + rb * 16 + quad * 4 + r;
      Om[(size_t)sb * NPIX + row] = mrun[rb][r];
      Ol[(size_t)sb * NPIX + row] = lrun[r];
    }
  }
}

// ---------------- K9: per-pixel merge scales across the 2 splits ----------------
__global__ void k_scales(const float* __restrict__ Om, const float* __restrict__ Ol,
                         float* __restrict__ sc0, float* __restrict__ sc1, int n) {
  int idx = blockIdx.x * 256 + threadIdx.x;
  if (idx >= n) return;                      // n = 2*NPIX; idx = b*NPIX+p
  int b = idx / NPIX; int p = idx % NPIX;
  float m0 = Om[(size_t)b * NPIX + p],       l0 = Ol[(size_t)b * NPIX + p];
  float m1 = Om[(size_t)(2 + b) * NPIX + p], l1 = Ol[(size_t)(2 + b) * NPIX + p];
  float m = fmaxf(m0, m1);
  float e0 = expf(10.f * (m0 - m)), e1 = expf(10.f * (m1 - m));
  float inv = 1.f / (l0 * e0 + l1 * e1);
  sc0[idx] = e0 * inv; sc1[idx] = e1 * inv;
}

// ---------------- K10: 9-tap gather with split-merge, /4, + residual ----------------
__global__ void k_final(const float* __restrict__ Og, const float* __restrict__ sc0,
                        const float* __restrict__ sc1, const float* __restrict__ input,
                        float* __restrict__ out, int n) {
  int idx = blockIdx.x * 256 + threadIdx.x;
  if (idx >= n) return;                      // n = 2*64*NPIX, idx = ((b*64+c)*64+y)*64+x
  int x = idx & 63; int y = (idx >> 6) & 63; int c = (idx >> 12) & 63; int b = idx >> 18;
  float acc = 0.f;
  for (int j = 0; j < 3; ++j) {
    int qy = y + 1 - j; if (qy < 0 || qy >= 64) continue;
    for (int i = 0; i < 3; ++i) {
      int qx = x + 1 - i; if (qx < 0 || qx >= 64) continue;
      int p = qy * 64 + qx;
      size_t e = ((size_t)b * NPIX + p) * 576 + c * 9 + j * 3 + i;
      float z = Og[e] * sc0[b * NPIX + p]
              + Og[(size_t)2 * NPIX * 576 + e] * sc1[b * NPIX + p];
      acc += z;
    }
  }
  out[idx] = 0.25f * acc + input[idx];
}

extern "C" void kernel_launch(void* const* d_in, const int* in_sizes, int n_in,
                              void* d_out, int out_size, void* d_ws, size_t ws_size,
                              hipStream_t stream) {
  (void)in_sizes; (void)n_in; (void)out_size; (void)ws_size;
  const float* input = (const float*)d_in[0];
  const float* inref = (const float*)d_in[1];
  const float* Wb = (const float*)d_in[2];
  const float* bb = (const float*)d_in[3];
  const float* Wm = (const float*)d_in[4];
  const float* bm = (const float*)d_in[5];
  const float* Wa = (const float*)d_in[6];
  const float* ba = (const float*)d_in[7];
  const float* ap = (const float*)d_in[8];
  float* out = (float*)d_out;

  char* ws = (char*)d_ws;
  size_t off = 0;
  auto alloc = [&](size_t bytes) -> char* {
    char* p = ws + off; off = (off + bytes + 255) & ~(size_t)255; return p;
  };
  float*    refbuf = (float*)alloc((size_t)2 * 64 * L_TOT * 4);
  float*    mref   = (float*)alloc((size_t)2 * 32 * L_TOT * 4);
  float*    aref   = (float*)alloc((size_t)2 * 64 * L_TOT * 4);
  float*    mbb    = (float*)alloc((size_t)2 * 32 * NPIX * 4);
  float*    ssq    = (float*)alloc((size_t)2 * L_TOT * 4);
  float*    invn   = (float*)alloc((size_t)2 * L_TOT * 4);
  ushort_t* Am     = (ushort_t*)alloc((size_t)2 * NPIX * 288 * 2);
  ushort_t* Bm     = (ushort_t*)alloc((size_t)2 * L_TOT * 288 * 2);
  ushort_t* Rm     = (ushort_t*)alloc((size_t)2 * 576 * L_PAD2 * 2);
  float*    Og     = (float*)alloc((size_t)4 * NPIX * 576 * 4);   // [split*2+b][p][col]
  float*    Om     = (float*)alloc((size_t)4 * NPIX * 4);
  float*    Ol     = (float*)alloc((size_t)4 * NPIX * 4);
  float*    sc0    = (float*)alloc((size_t)2 * NPIX * 4);
  float*    sc1    = (float*)alloc((size_t)2 * NPIX * 4);
  // total ~107 MB

  int n1 = 2 * 64 * L_TOT;
  k_resize<<<(n1 + 255) / 256, 256, 0, stream>>>(inref, refbuf, n1);
  int n2 = 2 * 96 * L_TOT;
  k_convref<<<(n2 + 255) / 256, 256, 0, stream>>>(refbuf, Wm, bm, Wa, ba, ap, mref, aref, n2);
  int n3 = 2 * 32 * NPIX;
  k_mb<<<(n3 + 255) / 256, 256, 0, stream>>>(input, Wb, bb, ap, mbb, n3);
  int n4 = 2 * L_TOT;
  k_ssq<<<(n4 + 255) / 256, 256, 0, stream>>>(mref, ssq, n4);
  k_invn<<<(n4 + 255) / 256, 256, 0, stream>>>(ssq, invn, n4);
  int n5 = 2 * L_TOT * 288;
  k_bim<<<(n5 + 255) / 256, 256, 0, stream>>>(mref, invn, Bm, n5);
  int n6 = 2 * NPIX * 288;
  k_aim<<<(n6 + 255) / 256, 256, 0, stream>>>(mbb, Am, n6);
  int n7 = 2 * 576 * L_PAD2;
  k_rim<<<(n7 + 255) / 256, 256, 0, stream>>>(aref, Rm, n7);

  k_attn<<<512, 256, 0, stream>>>(Am, Bm, Rm, Og, Om, Ol);
  k_scales<<<(2 * NPIX + 255) / 256, 256, 0, stream>>>(Om, Ol, sc0, sc1, 2 * NPIX);
  int no = 2 * 64 * NPIX;
  k_final<<<(no + 255) / 256, 256, 0, stream>>>(Og, sc0, sc1, input, out, no);
}